// Round 4
// baseline (392.834 us; speedup 1.0000x reference)
//
#include <hip/hip_runtime.h>
#include <hip/hip_bf16.h>
#include <hip/hip_cooperative_groups.h>

namespace cg = cooperative_groups;

#define D 1024
#define NB 256   // grid blocks (co-resident: <=1 block/CU)
#define TPB 512  // 8 waves/block

typedef unsigned int u32;
typedef __attribute__((ext_vector_type(4))) unsigned int u32x4;

__device__ __forceinline__ float bflo(u32 u) { return __uint_as_float(u << 16); }
__device__ __forceinline__ float bfhi(u32 u) { return __uint_as_float(u & 0xffff0000u); }
__device__ __forceinline__ float bf1(const void* p, int j) {
    unsigned short s = ((const unsigned short*)p)[j];
    return __uint_as_float(((u32)s) << 16);
}

__device__ __forceinline__ float waveReduceSum(float v) {
#pragma unroll
    for (int off = 32; off > 0; off >>= 1) v += __shfl_xor(v, off, 64);
    return v;
}

__device__ __forceinline__ void loadRow(const void* __restrict__ Hm, int r,
                                        int isBf16, int lane, float* h) {
    if (isBf16) {
        const u32x4* hr = (const u32x4*)((const __hip_bfloat16*)Hm + (size_t)r * D);
        u32x4 a = hr[lane];
        u32x4 b = hr[64 + lane];
#pragma unroll
        for (int t = 0; t < 4; ++t) {
            h[2 * t] = bflo(a[t]);     h[2 * t + 1] = bfhi(a[t]);
            h[8 + 2 * t] = bflo(b[t]); h[8 + 2 * t + 1] = bfhi(b[t]);
        }
    } else {
        const float4* hr = (const float4*)((const float*)Hm + (size_t)r * D);
#pragma unroll
        for (int t = 0; t < 4; ++t) {
            float4 a = hr[t * 64 + lane];
            h[t * 4 + 0] = a.x; h[t * 4 + 1] = a.y;
            h[t * 4 + 2] = a.z; h[t * 4 + 3] = a.w;
        }
    }
}

__device__ __forceinline__ float dotTree(const float* h, const float* qr) {
    float p[16];
#pragma unroll
    for (int j = 0; j < 16; ++j) p[j] = h[j] * qr[j];
#pragma unroll
    for (int step = 1; step < 16; step <<= 1)
#pragma unroll
        for (int j = 0; j < 16; j += 2 * step) p[j] += p[j + step];
    return p[0];
}

// row-dot: dot(Wrow[j,:], vec from global fp32 e / or second operand pairs)
__global__ __launch_bounds__(TPB) void k_all(
    const void* __restrict__ Hm, const void* __restrict__ ht,
    const void* __restrict__ W0, const void* __restrict__ b0,
    const void* __restrict__ W1, const void* __restrict__ b1,
    const void* __restrict__ W2, const void* __restrict__ b2,
    void* __restrict__ out,
    float* __restrict__ q, float* __restrict__ accp,   // accp[NB][D]
    float* __restrict__ lvals, float* __restrict__ e_s,
    float* __restrict__ Ls, int N) {
    cg::grid_group grid = cg::this_grid();
    __shared__ float lacc[8][D];
    __shared__ float ll[8];
    __shared__ float4 redf[4];
    int wid = threadIdx.x >> 6, lane = threadIdx.x & 63;

    // ---- dtype probe (per-wave, 6 shuffles; bf16 low-half exponents are sane) ----
    int isBf16;
    {
        u32 w = ((const u32*)ht)[lane];
        u32 e = (w >> 7) & 0xFF;
        float c = (e >= 100 && e <= 126) ? 1.f : 0.f;
        c = waveReduceSum(c);
        isBf16 = (c >= 56.f) ? 1 : 0;
    }

    // ---- phase 1: q[j] = dot(W0[j,:], h_t) + b0[j]  (waves 0-3, 1024 rows) ----
    if (wid < 4) {
        int j = blockIdx.x * 4 + wid;
        float s = 0.f;
        if (isBf16) {
            const u32x4* wrow = (const u32x4*)((const __hip_bfloat16*)W0 + (size_t)j * D);
            const u32x4* hv = (const u32x4*)ht;
#pragma unroll
            for (int half = 0; half < 2; ++half) {
                u32x4 a = wrow[half * 64 + lane];
                u32x4 b = hv[half * 64 + lane];
#pragma unroll
                for (int t = 0; t < 4; ++t) {
                    s += bflo(a[t]) * bflo(b[t]);
                    s += bfhi(a[t]) * bfhi(b[t]);
                }
            }
        } else {
            const float4* wrow = (const float4*)((const float*)W0 + (size_t)j * D);
            const float4* hv = (const float4*)ht;
#pragma unroll
            for (int t = 0; t < 4; ++t) {
                float4 a = wrow[t * 64 + lane];
                float4 b = hv[t * 64 + lane];
                s += a.x * b.x + a.y * b.y + a.z * b.z + a.w * b.w;
            }
        }
        s = waveReduceSum(s);
        if (lane == 0) {
            float bias = isBf16 ? bf1(b0, j) : ((const float*)b0)[j];
            q[j] = s + bias;
        }
    }
    grid.sync();

    // ---- phase 2: fused pass, w_i = exp(exp(H_i.q)); block partials ----
    {
        int col[16];
        if (isBf16) {
#pragma unroll
            for (int j = 0; j < 8; ++j) { col[j] = lane * 8 + j; col[8 + j] = 512 + lane * 8 + j; }
        } else {
#pragma unroll
            for (int t = 0; t < 4; ++t)
#pragma unroll
                for (int u = 0; u < 4; ++u) col[t * 4 + u] = t * 256 + lane * 4 + u;
        }
        float qr[16];
#pragma unroll
        for (int j = 0; j < 16; ++j) qr[j] = q[col[j]];

        float l = 0.f;
        float acc[16];
#pragma unroll
        for (int j = 0; j < 16; ++j) acc[j] = 0.f;

        const int totalWaves = NB * 8;
        int gw = blockIdx.x * 8 + wid;
        int r = gw;
        for (; r + totalWaves < N; r += 2 * totalWaves) {
            float h0[16], h1[16];
            loadRow(Hm, r, isBf16, lane, h0);
            loadRow(Hm, r + totalWaves, isBf16, lane, h1);
            float d0 = dotTree(h0, qr);
            float d1 = dotTree(h1, qr);
            d0 = waveReduceSum(d0);
            d1 = waveReduceSum(d1);
            float p0 = __expf(__expf(d0));
            float p1 = __expf(__expf(d1));
            l += p0 + p1;
#pragma unroll
            for (int j = 0; j < 16; ++j) acc[j] += p0 * h0[j] + p1 * h1[j];
        }
        if (r < N) {
            float h0[16];
            loadRow(Hm, r, isBf16, lane, h0);
            float d0 = waveReduceSum(dotTree(h0, qr));
            float p0 = __expf(__expf(d0));
            l += p0;
#pragma unroll
            for (int j = 0; j < 16; ++j) acc[j] += p0 * h0[j];
        }

#pragma unroll
        for (int j = 0; j < 16; ++j) lacc[wid][col[j]] = acc[j];
        if (lane == 0) ll[wid] = l;
        __syncthreads();
        float* dst = accp + (size_t)blockIdx.x * D;
        for (int k = threadIdx.x; k < D; k += TPB) {
            float s = 0.f;
#pragma unroll
            for (int w = 0; w < 8; ++w) s += lacc[w][k];
            dst[k] = s;
        }
        if (threadIdx.x == 0) {
            float s = 0.f;
#pragma unroll
            for (int w = 0; w < 8; ++w) s += ll[w];
            lvals[blockIdx.x] = s;
        }
    }
    grid.sync();

    // ---- phase 3: e_s[4g..4g+3] = sum_b accp[b][col]; Ls = sum lvals ----
    {
        if (threadIdx.x < 256) {
            float4 v = *(const float4*)(accp + (size_t)threadIdx.x * D + blockIdx.x * 4);
            v.x = waveReduceSum(v.x);
            v.y = waveReduceSum(v.y);
            v.z = waveReduceSum(v.z);
            v.w = waveReduceSum(v.w);
            if (lane == 0) redf[wid] = v;
        }
        if (blockIdx.x == 0 && wid == 4) {
            float ls = lvals[lane] + lvals[lane + 64] + lvals[lane + 128] + lvals[lane + 192];
            ls = waveReduceSum(ls);
            if (lane == 0) *Ls = ls;
        }
        __syncthreads();
        if (threadIdx.x == 0) {
            float4 a = redf[0], b = redf[1], c = redf[2], d = redf[3];
            float4 r;
            r.x = a.x + b.x + c.x + d.x;
            r.y = a.y + b.y + c.y + d.y;
            r.z = a.z + b.z + c.z + d.z;
            r.w = a.w + b.w + c.w + d.w;
            *(float4*)(e_s + blockIdx.x * 4) = r;
        }
    }
    grid.sync();

    // ---- phase 4: out[j] = tanh(W1[j].e_s/Ls + b1[j] + W2[j].h_t + b2[j]) ----
    if (wid < 4) {
        int j = blockIdx.x * 4 + wid;
        float s1 = 0.f, s2 = 0.f;
        if (isBf16) {
            const u32x4* w1r = (const u32x4*)((const __hip_bfloat16*)W1 + (size_t)j * D);
            const u32x4* w2r = (const u32x4*)((const __hip_bfloat16*)W2 + (size_t)j * D);
            const u32x4* hv = (const u32x4*)ht;
            int c0 = lane * 8;
#pragma unroll
            for (int half = 0; half < 2; ++half) {
                u32x4 a = w1r[half * 64 + lane];
                u32x4 b = w2r[half * 64 + lane];
                u32x4 hh = hv[half * 64 + lane];
                const float4* ev = (const float4*)(e_s + half * 512 + c0);
                float4 ea = ev[0], eb = ev[1];
                float e[8] = {ea.x, ea.y, ea.z, ea.w, eb.x, eb.y, eb.z, eb.w};
#pragma unroll
                for (int t = 0; t < 4; ++t) {
                    s1 += bflo(a[t]) * e[2 * t] + bfhi(a[t]) * e[2 * t + 1];
                    s2 += bflo(b[t]) * bflo(hh[t]) + bfhi(b[t]) * bfhi(hh[t]);
                }
            }
        } else {
            const float4* w1r = (const float4*)((const float*)W1 + (size_t)j * D);
            const float4* w2r = (const float4*)((const float*)W2 + (size_t)j * D);
            const float4* hv = (const float4*)ht;
            const float4* ev = (const float4*)e_s;
#pragma unroll
            for (int t = 0; t < 4; ++t) {
                float4 a = w1r[t * 64 + lane];
                float4 b = w2r[t * 64 + lane];
                float4 hh = hv[t * 64 + lane];
                float4 ee = ev[t * 64 + lane];
                s1 += a.x * ee.x + a.y * ee.y + a.z * ee.z + a.w * ee.w;
                s2 += b.x * hh.x + b.y * hh.y + b.z * hh.z + b.w * hh.w;
            }
        }
        s1 = waveReduceSum(s1);
        s2 = waveReduceSum(s2);
        if (lane == 0) {
            float bias1 = isBf16 ? bf1(b1, j) : ((const float*)b1)[j];
            float bias2 = isBf16 ? bf1(b2, j) : ((const float*)b2)[j];
            float r = tanhf(s1 / (*Ls) + bias1 + s2 + bias2);
            if (isBf16) ((__hip_bfloat16*)out)[j] = __float2bfloat16(r);
            else        ((float*)out)[j] = r;
        }
    }
}

extern "C" void kernel_launch(void* const* d_in, const int* in_sizes, int n_in,
                              void* d_out, int out_size, void* d_ws, size_t ws_size,
                              hipStream_t stream) {
    const void* H  = d_in[0];
    const void* ht = d_in[1];
    const void* W0 = d_in[2];
    const void* b0 = d_in[3];
    const void* W1 = d_in[4];
    const void* b1 = d_in[5];
    const void* W2 = d_in[6];
    const void* b2 = d_in[7];
    void* out = d_out;
    int N = in_sizes[0] / D;

    float* wsf   = (float*)d_ws;
    float* q     = wsf;            // [1024]
    float* e_s   = wsf + 1024;     // [1024]
    float* Ls    = wsf + 2048;     // [1]
    float* lvals = wsf + 2112;     // [NB]
    float* accp  = wsf + 4096;     // [NB][1024]

    void* args[] = {(void*)&H, (void*)&ht, (void*)&W0, (void*)&b0,
                    (void*)&W1, (void*)&b1, (void*)&W2, (void*)&b2,
                    (void*)&out, (void*)&q, (void*)&accp, (void*)&lvals,
                    (void*)&e_s, (void*)&Ls, (void*)&N};
    hipLaunchCooperativeKernel((const void*)k_all, dim3(NB), dim3(TPB),
                               args, 0, stream);
}

// Round 5
// 370.557 us; speedup vs baseline: 1.0601x; 1.0601x over previous
//
#include <hip/hip_runtime.h>
#include <hip/hip_bf16.h>

#define D 1024

typedef unsigned int u32;
typedef __attribute__((ext_vector_type(4))) unsigned int u32x4;
typedef __attribute__((ext_vector_type(4))) unsigned short u16x4;

__device__ __forceinline__ float bflo(u32 u) { return __uint_as_float(u << 16); }
__device__ __forceinline__ float bfhi(u32 u) { return __uint_as_float(u & 0xffff0000u); }
__device__ __forceinline__ float bf1(const void* p, int j) {
    unsigned short s = ((const unsigned short*)p)[j];
    return __uint_as_float(((u32)s) << 16);
}

__device__ __forceinline__ float waveReduceSum(float v) {
#pragma unroll
    for (int off = 32; off > 0; off >>= 1) v += __shfl_xor(v, off, 64);
    return v;
}

// dtype probe: bf16 low-half exponents sane; fp32 low halves ~random.
__global__ __launch_bounds__(64) void k_probe(const u32* __restrict__ htw,
                                              int* __restrict__ flag) {
    int lane = threadIdx.x;
    u32 w = htw[lane];
    u32 e = (w >> 7) & 0xFF;
    float c = (e >= 100 && e <= 126) ? 1.f : 0.f;
    c = waveReduceSum(c);
    if (lane == 0) *flag = (c >= 56.f) ? 1 : 0;
}

// q[j] = dot(W0[j,:], h_t) + b0[j]
__global__ __launch_bounds__(256) void k_q(const int* __restrict__ flag,
                                           const void* __restrict__ W0,
                                           const void* __restrict__ ht,
                                           const void* __restrict__ b0,
                                           float* __restrict__ q) {
    int wid = threadIdx.x >> 6, lane = threadIdx.x & 63;
    int j = blockIdx.x * 4 + wid;
    int isBf16 = *flag;
    float s = 0.f;
    if (isBf16) {
        const u32x4* wrow = (const u32x4*)((const __hip_bfloat16*)W0 + (size_t)j * D);
        const u32x4* hv = (const u32x4*)ht;
#pragma unroll
        for (int half = 0; half < 2; ++half) {
            u32x4 a = wrow[half * 64 + lane];
            u32x4 b = hv[half * 64 + lane];
#pragma unroll
            for (int t = 0; t < 4; ++t) {
                s += bflo(a[t]) * bflo(b[t]);
                s += bfhi(a[t]) * bfhi(b[t]);
            }
        }
    } else {
        const float4* wrow = (const float4*)((const float*)W0 + (size_t)j * D);
        const float4* hv = (const float4*)ht;
#pragma unroll
        for (int t = 0; t < 4; ++t) {
            float4 a = wrow[t * 64 + lane];
            float4 b = hv[t * 64 + lane];
            s += a.x * b.x + a.y * b.y + a.z * b.z + a.w * b.w;
        }
    }
    s = waveReduceSum(s);
    if (lane == 0) {
        float bias = isBf16 ? bf1(b0, j) : ((const float*)b0)[j];
        q[j] = s + bias;
    }
}

// w[r] = exp(exp(H[r].q)); per-block sum of w -> lvals[block].
// Each wave: 16 rows (two groups of 8 independent shuffle-reduce chains).
__global__ __launch_bounds__(256) void k_score(const int* __restrict__ flag,
                                               const void* __restrict__ Hm,
                                               const float* __restrict__ q,
                                               float* __restrict__ w,
                                               float* __restrict__ lvals,
                                               int N) {
    __shared__ float ls[4];
    int wid = threadIdx.x >> 6, lane = threadIdx.x & 63;
    int gw = blockIdx.x * 4 + wid;
    int isBf16 = *flag;

    float qr[16];
    if (isBf16) {
#pragma unroll
        for (int j = 0; j < 8; ++j) {
            qr[j] = q[lane * 8 + j];
            qr[8 + j] = q[512 + lane * 8 + j];
        }
    } else {
#pragma unroll
        for (int t = 0; t < 4; ++t)
#pragma unroll
            for (int u = 0; u < 4; ++u) qr[t * 4 + u] = q[t * 256 + lane * 4 + u];
    }

    float lsum = 0.f;
#pragma unroll
    for (int half = 0; half < 2; ++half) {
        int r0 = gw * 16 + half * 8;
        float d[8];
#pragma unroll
        for (int i = 0; i < 8; ++i) {
            int r = r0 + i;
            float dd = 0.f;
            if (r < N) {
                if (isBf16) {
                    const u32x4* hr = (const u32x4*)((const __hip_bfloat16*)Hm + (size_t)r * D);
                    u32x4 a = hr[lane];
                    u32x4 b = hr[64 + lane];
#pragma unroll
                    for (int t = 0; t < 4; ++t) {
                        dd += bflo(a[t]) * qr[2 * t] + bfhi(a[t]) * qr[2 * t + 1];
                        dd += bflo(b[t]) * qr[8 + 2 * t] + bfhi(b[t]) * qr[8 + 2 * t + 1];
                    }
                } else {
                    const float4* hr = (const float4*)((const float*)Hm + (size_t)r * D);
#pragma unroll
                    for (int t = 0; t < 4; ++t) {
                        float4 a = hr[t * 64 + lane];
                        dd += a.x * qr[t * 4] + a.y * qr[t * 4 + 1] +
                              a.z * qr[t * 4 + 2] + a.w * qr[t * 4 + 3];
                    }
                }
            }
            d[i] = dd;
        }
        // 8 independent butterfly chains; compiler interleaves -> DS throughput-bound
#pragma unroll
        for (int off = 32; off > 0; off >>= 1) {
#pragma unroll
            for (int i = 0; i < 8; ++i) d[i] += __shfl_xor(d[i], off, 64);
        }
        float p[8];
#pragma unroll
        for (int i = 0; i < 8; ++i) p[i] = __expf(__expf(d[i]));
        if (r0 + 8 <= N) {
            if (lane == 0) {
                float4 w0 = {p[0], p[1], p[2], p[3]};
                float4 w1 = {p[4], p[5], p[6], p[7]};
                *(float4*)(w + r0) = w0;
                *(float4*)(w + r0 + 4) = w1;
            }
#pragma unroll
            for (int i = 0; i < 8; ++i) lsum += p[i];
        } else {
#pragma unroll
            for (int i = 0; i < 8; ++i) {
                if (r0 + i < N) {
                    if (lane == 0) w[r0 + i] = p[i];
                    lsum += p[i];
                }
            }
        }
    }
    if (lane == 0) ls[wid] = lsum;
    __syncthreads();
    if (threadIdx.x == 0) lvals[blockIdx.x] = ls[0] + ls[1] + ls[2] + ls[3];
}

// Weighted column sum, no cross-lane ops. Thread t owns cols 4t..4t+3.
// Block b handles rows [b*rpb, min(N,(b+1)*rpb)); writes accp[b][1024].
__global__ __launch_bounds__(256) void k_wsum(const int* __restrict__ flag,
                                              const void* __restrict__ Hm,
                                              const float* __restrict__ w,
                                              float* __restrict__ accp,
                                              int N, int rpb) {
    int isBf16 = *flag;
    int c = threadIdx.x * 4;
    int rb = blockIdx.x * rpb;
    int re = min(N, rb + rpb);
    float a0 = 0.f, a1 = 0.f, a2 = 0.f, a3 = 0.f;
    int r = rb;
    if (isBf16) {
        const unsigned short* Hb = (const unsigned short*)Hm;
        for (; r + 8 <= re; r += 8) {
#pragma unroll
            for (int i = 0; i < 8; ++i) {
                float wr = w[r + i];  // uniform -> scalar load
                u16x4 hv = *(const u16x4*)(Hb + (size_t)(r + i) * D + c);
                a0 += wr * __uint_as_float(((u32)hv[0]) << 16);
                a1 += wr * __uint_as_float(((u32)hv[1]) << 16);
                a2 += wr * __uint_as_float(((u32)hv[2]) << 16);
                a3 += wr * __uint_as_float(((u32)hv[3]) << 16);
            }
        }
        for (; r < re; ++r) {
            float wr = w[r];
            u16x4 hv = *(const u16x4*)(Hb + (size_t)r * D + c);
            a0 += wr * __uint_as_float(((u32)hv[0]) << 16);
            a1 += wr * __uint_as_float(((u32)hv[1]) << 16);
            a2 += wr * __uint_as_float(((u32)hv[2]) << 16);
            a3 += wr * __uint_as_float(((u32)hv[3]) << 16);
        }
    } else {
        const float* Hf = (const float*)Hm;
        for (; r + 8 <= re; r += 8) {
#pragma unroll
            for (int i = 0; i < 8; ++i) {
                float wr = w[r + i];
                float4 hv = *(const float4*)(Hf + (size_t)(r + i) * D + c);
                a0 += wr * hv.x; a1 += wr * hv.y; a2 += wr * hv.z; a3 += wr * hv.w;
            }
        }
        for (; r < re; ++r) {
            float wr = w[r];
            float4 hv = *(const float4*)(Hf + (size_t)r * D + c);
            a0 += wr * hv.x; a1 += wr * hv.y; a2 += wr * hv.z; a3 += wr * hv.w;
        }
    }
    float4 res = {a0, a1, a2, a3};
    *(float4*)(accp + (size_t)blockIdx.x * D + c) = res;
}

// e_s[k] = sum_b accp[b][k]; Ls = sum lvals. grid = D/64 blocks.
__global__ __launch_bounds__(256) void k_fin(const float* __restrict__ accp,
                                             const float* __restrict__ lvals,
                                             float* __restrict__ e_s,
                                             float* __restrict__ Ls,
                                             int B, int NL) {
    __shared__ float part[4][64];
    int t = threadIdx.x, lane = t & 63, chunk = t >> 6;
    int col = blockIdx.x * 64 + lane;
    int rpc = B >> 2;
    float s = 0.f;
    for (int b = chunk * rpc; b < (chunk + 1) * rpc; ++b)
        s += accp[(size_t)b * D + col];
    part[chunk][lane] = s;
    __syncthreads();
    if (t < 64) e_s[col] = part[0][lane] + part[1][lane] + part[2][lane] + part[3][lane];
    if (blockIdx.x == 0 && chunk == 3) {
        float ls = 0.f;
        for (int b = lane; b < NL; b += 64) ls += lvals[b];
        ls = waveReduceSum(ls);
        if (lane == 0) *Ls = ls;
    }
}

// out[j] = tanh(dot(W1[j],e_s)/Ls + b1[j] + dot(W2[j],h_t) + b2[j])
__global__ __launch_bounds__(256) void k_out(const int* __restrict__ flag,
                                             const void* __restrict__ W1,
                                             const void* __restrict__ b1,
                                             const void* __restrict__ W2,
                                             const void* __restrict__ b2,
                                             const void* __restrict__ ht,
                                             const float* __restrict__ e_s,
                                             const float* __restrict__ Ls,
                                             void* __restrict__ out) {
    int wid = threadIdx.x >> 6, lane = threadIdx.x & 63;
    int j = blockIdx.x * 4 + wid;
    int isBf16 = *flag;
    float s1 = 0.f, s2 = 0.f;
    if (isBf16) {
        const u32x4* w1r = (const u32x4*)((const __hip_bfloat16*)W1 + (size_t)j * D);
        const u32x4* w2r = (const u32x4*)((const __hip_bfloat16*)W2 + (size_t)j * D);
        const u32x4* hv = (const u32x4*)ht;
        int c0 = lane * 8;
#pragma unroll
        for (int half = 0; half < 2; ++half) {
            u32x4 a = w1r[half * 64 + lane];
            u32x4 b = w2r[half * 64 + lane];
            u32x4 hh = hv[half * 64 + lane];
            const float4* ev = (const float4*)(e_s + half * 512 + c0);
            float4 ea = ev[0], eb = ev[1];
            float e[8] = {ea.x, ea.y, ea.z, ea.w, eb.x, eb.y, eb.z, eb.w};
#pragma unroll
            for (int t = 0; t < 4; ++t) {
                s1 += bflo(a[t]) * e[2 * t] + bfhi(a[t]) * e[2 * t + 1];
                s2 += bflo(b[t]) * bflo(hh[t]) + bfhi(b[t]) * bfhi(hh[t]);
            }
        }
    } else {
        const float4* w1r = (const float4*)((const float*)W1 + (size_t)j * D);
        const float4* w2r = (const float4*)((const float*)W2 + (size_t)j * D);
        const float4* hv = (const float4*)ht;
        const float4* ev = (const float4*)e_s;
#pragma unroll
        for (int t = 0; t < 4; ++t) {
            float4 a = w1r[t * 64 + lane];
            float4 b = w2r[t * 64 + lane];
            float4 hh = hv[t * 64 + lane];
            float4 ee = ev[t * 64 + lane];
            s1 += a.x * ee.x + a.y * ee.y + a.z * ee.z + a.w * ee.w;
            s2 += b.x * hh.x + b.y * hh.y + b.z * hh.z + b.w * hh.w;
        }
    }
    s1 = waveReduceSum(s1);
    s2 = waveReduceSum(s2);
    if (lane == 0) {
        float bias1 = isBf16 ? bf1(b1, j) : ((const float*)b1)[j];
        float bias2 = isBf16 ? bf1(b2, j) : ((const float*)b2)[j];
        float r = tanhf(s1 / (*Ls) + bias1 + s2 + bias2);
        if (isBf16) ((__hip_bfloat16*)out)[j] = __float2bfloat16(r);
        else        ((float*)out)[j] = r;
    }
}

extern "C" void kernel_launch(void* const* d_in, const int* in_sizes, int n_in,
                              void* d_out, int out_size, void* d_ws, size_t ws_size,
                              hipStream_t stream) {
    const void* H  = d_in[0];
    const void* ht = d_in[1];
    const void* W0 = d_in[2];
    const void* b0 = d_in[3];
    const void* W1 = d_in[4];
    const void* b1 = d_in[5];
    const void* W2 = d_in[6];
    const void* b2 = d_in[7];
    int N = in_sizes[0] / D;

    const int WSB = 512;                 // k_wsum blocks
    int rpb = (N + WSB - 1) / WSB;       // rows per k_wsum block
    int nsc = (N + 63) / 64;             // k_score blocks (4 waves x 16 rows)

    float* wsf   = (float*)d_ws;
    int*   flag  = (int*)wsf;            // [1]
    float* Ls    = wsf + 1;              // [1]
    float* q     = wsf + 64;             // [1024]
    float* e_s   = wsf + 1088;           // [1024]
    float* lvals = wsf + 2112;           // [nsc] (<=1024)
    float* w     = wsf + 3136;           // [N]
    float* accp  = wsf + 3136 + ((N + 63) & ~63);  // [WSB][1024]

    k_probe<<<1, 64, 0, stream>>>((const u32*)ht, flag);
    k_q<<<256, 256, 0, stream>>>(flag, W0, ht, b0, q);
    k_score<<<nsc, 256, 0, stream>>>(flag, H, q, w, lvals, N);
    k_wsum<<<WSB, 256, 0, stream>>>(flag, H, w, accp, N, rpb);
    k_fin<<<D / 64, 256, 0, stream>>>(accp, lvals, e_s, Ls, WSB, nsc);
    k_out<<<256, 256, 0, stream>>>(flag, W1, b1, W2, b2, ht, e_s, Ls, d_out);
}